// Round 1
// baseline (725.926 us; speedup 1.0000x reference)
//
#include <hip/hip_runtime.h>
#include <cmath>

namespace {

constexpr int kB = 64;
constexpr int kM = 16384;
constexpr int kW = 128;
constexpr int kH = 8;
constexpr float kEps = 1e-6f;

// ---------------------------------------------------------------------------
// K0: per (b,h) key norm + softplus(strength) into ws.
// ws[0 .. 511]    = ||keys[b,h]||
// ws[512 .. 1023] = softplus(strengths[b,h])
// Grid: kB blocks x 256 threads (8 heads x 32 lanes each).
__global__ __launch_bounds__(256) void cw_stats(
    const float* __restrict__ keys,
    const float* __restrict__ strengths,
    float* __restrict__ ws)
{
  const int b = blockIdx.x;
  const int t = threadIdx.x;
  const int h = t >> 5, p = t & 31;  // 32 lanes per head, xor-shuffles stay inside the group
  const float4 v = ((const float4*)(keys + ((size_t)b * kH + h) * kW))[p];
  float a = v.x * v.x + v.y * v.y + v.z * v.z + v.w * v.w;
  #pragma unroll
  for (int off = 16; off > 0; off >>= 1) a += __shfl_xor(a, off);
  if (p == 0) {
    ws[b * kH + h] = sqrtf(a);
    const float x = strengths[b * kH + h];
    ws[kB * kH + b * kH + h] = fmaxf(x, 0.f) + log1pf(__expf(-fabsf(x)));
  }
}

// ---------------------------------------------------------------------------
// K1: weighted cosine scores (pre-softmax) into out.
// Thread-per-slot streaming version: zero LDS, zero barriers, zero cross-
// thread reduction.
//  - lane t owns slot m0+t over the full W=128: dots + norm accumulate in
//    registers (split even/odd chunk-group accumulators to keep FMA chains
//    at 64 for precision).
//  - memory read directly from global: 32 float4 per thread; the 4 chunk
//    loads of each group share one 64B line -> L1 merges, every line fully
//    consumed, full HBM BW.
//  - keys indexed only by (blockIdx, compile-time h,c) -> compiler emits
//    s_load into SGPRs (sL1-cached); v_fma takes the key as its one SGPR
//    operand. No LDS broadcast traffic at all.
//  - out stores: 8 perfectly-coalesced dword stores per thread.
// Grid: kB * (kM/256) = 4096 blocks x 256 threads.
// __launch_bounds__(256,4): cap 128 VGPR -> 4 blocks/CU = 16 waves/CU.
__global__ __launch_bounds__(256, 4) void cw_scores(
    const float* __restrict__ mem,
    const float* __restrict__ keys,
    const float* __restrict__ ws,
    float* __restrict__ out)
{
  const int t = threadIdx.x;
  const int b = blockIdx.x >> 6;                  // 64 m-tiles per batch
  const int m = ((blockIdx.x & 63) << 8) + t;     // 256 slots per block

  const float4* __restrict__ gm =
      (const float4*)(mem + ((size_t)b * kM + m) * kW);
  const float* __restrict__ kb = keys + (size_t)b * kH * kW;

  float d0[kH], d1[kH];
  float n0 = 0.f, n1 = 0.f;
  #pragma unroll
  for (int h = 0; h < kH; ++h) { d0[h] = 0.f; d1[h] = 0.f; }

  #pragma unroll
  for (int cg = 0; cg < 8; ++cg) {
    float4 v[4];
    #pragma unroll
    for (int j = 0; j < 4; ++j) v[j] = gm[cg * 4 + j];

    #pragma unroll
    for (int j = 0; j < 4; ++j) {
      const int c4 = (cg * 4 + j) * 4;
      if (cg & 1) {
        n1 = fmaf(v[j].x, v[j].x, fmaf(v[j].y, v[j].y,
             fmaf(v[j].z, v[j].z, fmaf(v[j].w, v[j].w, n1))));
      } else {
        n0 = fmaf(v[j].x, v[j].x, fmaf(v[j].y, v[j].y,
             fmaf(v[j].z, v[j].z, fmaf(v[j].w, v[j].w, n0))));
      }
      #pragma unroll
      for (int h = 0; h < kH; ++h) {
        const float k0 = kb[h * kW + c4 + 0];   // wave-uniform -> s_load
        const float k1 = kb[h * kW + c4 + 1];
        const float k2 = kb[h * kW + c4 + 2];
        const float k3 = kb[h * kW + c4 + 3];
        if (cg & 1) {
          d1[h] = fmaf(v[j].x, k0, fmaf(v[j].y, k1,
                  fmaf(v[j].z, k2, fmaf(v[j].w, k3, d1[h]))));
        } else {
          d0[h] = fmaf(v[j].x, k0, fmaf(v[j].y, k1,
                  fmaf(v[j].z, k2, fmaf(v[j].w, k3, d0[h]))));
        }
      }
    }
  }

  const float nrm = sqrtf(n0 + n1);
  float* op = out + (size_t)b * kH * kM + m;
  #pragma unroll
  for (int h = 0; h < kH; ++h) {
    const float kn  = ws[b * kH + h];             // uniform -> s_load
    const float adj = ws[kB * kH + b * kH + h];
    op[(size_t)h * kM] = adj * (d0[h] + d1[h]) / fmaf(nrm, kn, kEps);
  }
}

// ---------------------------------------------------------------------------
// K2: in-place softmax over M per (b,h) row. Grid: kB*kH blocks x 256 threads.
// Whole row (16384 f32) lives in registers: 16 float4 per thread.
__global__ __launch_bounds__(256) void cw_softmax(float* __restrict__ out)
{
  __shared__ float red[16];

  const int tid = threadIdx.x;
  const int wave = tid >> 6, lane = tid & 63;
  float4* p4 = (float4*)(out + (size_t)blockIdx.x * kM);

  float4 vs[16];
  float lmax = -INFINITY;
  #pragma unroll
  for (int k = 0; k < 16; ++k) {
    vs[k] = p4[k * 256 + tid];
    lmax = fmaxf(lmax, fmaxf(fmaxf(vs[k].x, vs[k].y), fmaxf(vs[k].z, vs[k].w)));
  }
  #pragma unroll
  for (int off = 32; off > 0; off >>= 1) lmax = fmaxf(lmax, __shfl_xor(lmax, off));
  if (lane == 0) red[wave] = lmax;
  __syncthreads();
  const float bmax = fmaxf(fmaxf(red[0], red[1]), fmaxf(red[2], red[3]));

  float lsum = 0.f;
  #pragma unroll
  for (int k = 0; k < 16; ++k) {
    vs[k].x = __expf(vs[k].x - bmax);
    vs[k].y = __expf(vs[k].y - bmax);
    vs[k].z = __expf(vs[k].z - bmax);
    vs[k].w = __expf(vs[k].w - bmax);
    lsum += (vs[k].x + vs[k].y) + (vs[k].z + vs[k].w);
  }
  #pragma unroll
  for (int off = 32; off > 0; off >>= 1) lsum += __shfl_xor(lsum, off);
  if (lane == 0) red[8 + wave] = lsum;
  __syncthreads();
  const float inv = 1.f / ((red[8] + red[9]) + (red[10] + red[11]));

  #pragma unroll
  for (int k = 0; k < 16; ++k) {
    vs[k].x *= inv; vs[k].y *= inv; vs[k].z *= inv; vs[k].w *= inv;
    p4[k * 256 + tid] = vs[k];
  }
}

}  // namespace

extern "C" void kernel_launch(void* const* d_in, const int* in_sizes, int n_in,
                              void* d_out, int out_size, void* d_ws, size_t ws_size,
                              hipStream_t stream) {
  (void)in_sizes; (void)n_in; (void)ws_size; (void)out_size;
  const float* mem       = (const float*)d_in[0];
  const float* keys      = (const float*)d_in[1];
  const float* strengths = (const float*)d_in[2];
  float* out = (float*)d_out;
  float* wsf = (float*)d_ws;  // 1024 floats: [kn | adj]

  cw_stats<<<dim3(kB), dim3(256), 0, stream>>>(keys, strengths, wsf);
  cw_scores<<<dim3(kB * (kM / 256)), dim3(256), 0, stream>>>(mem, keys, wsf, out);
  cw_softmax<<<dim3(kB * kH), dim3(256), 0, stream>>>(out);
}